// Round 13
// baseline (219.366 us; speedup 1.0000x reference)
//
#include <hip/hip_runtime.h>
#include <stdint.h>

#define B_ 2
#define L_ 2048
#define DM 1024
#define NH 16
#define DH 64
#define M_ (B_*L_)     // 4096
#define NQKV 3072

typedef short short8 __attribute__((ext_vector_type(8)));
typedef float f32x4 __attribute__((ext_vector_type(4)));

__device__ __forceinline__ unsigned short f2b(float f) {
    union { float f; unsigned int u; } v; v.f = f;
    unsigned int u = v.u;
    return (unsigned short)((u + 0x7fffu + ((u >> 16) & 1u)) >> 16);   // RNE
}

__device__ __forceinline__ void gld_lds16(const void* g, void* l) {
    __builtin_amdgcn_global_load_lds(
        (const __attribute__((address_space(1))) void*)g,
        (__attribute__((address_space(3))) void*)l, 16, 0, 0);
}

// ---------------- fused setup (round-7 proven; + done[] zero) ----------------
__global__ __launch_bounds__(256)
void setup_kernel(const float* __restrict__ x,
                  const float* __restrict__ Wq, const float* __restrict__ Wk,
                  const float* __restrict__ Wv, const float* __restrict__ Wo,
                  const float* __restrict__ bq, const float* __restrict__ bk,
                  const float* __restrict__ bv,
                  unsigned short* __restrict__ xb, unsigned short* __restrict__ WqkvT,
                  unsigned short* __restrict__ WoT, float* __restrict__ biasq,
                  float* __restrict__ KtV, unsigned* __restrict__ done)
{
    __shared__ float tile[32][33];
    const int bid = blockIdx.x;
    const int t = threadIdx.x;

    if (bid < 2048) {
        int i = (bid * 256 + t) * 8;
        float4 a0 = *(const float4*)(x + i);
        float4 a1 = *(const float4*)(x + i + 4);
        uint4 p;
        p.x = (unsigned)f2b(a0.x) | ((unsigned)f2b(a0.y) << 16);
        p.y = (unsigned)f2b(a0.z) | ((unsigned)f2b(a0.w) << 16);
        p.z = (unsigned)f2b(a1.x) | ((unsigned)f2b(a1.y) << 16);
        p.w = (unsigned)f2b(a1.z) | ((unsigned)f2b(a1.w) << 16);
        *(uint4*)(xb + i) = p;
    } else if (bid < 2048 + 4096) {
        int wb = bid - 2048;
        int wi = wb >> 10;                // 0=Wq 1=Wk 2=Wv 3=Wo
        int tid = wb & 1023;
        const float* W = (wi == 0) ? Wq : (wi == 1) ? Wk : (wi == 2) ? Wv : Wo;
        float s = (wi == 1) ? 0.125f : 1.0f;
        int n0 = (tid & 31) * 32, k0 = (tid >> 5) * 32;
        int r = t >> 3, c4 = (t & 7) << 2;
        float4 v = *(const float4*)(W + (size_t)(k0 + r) * DM + n0 + c4);
        tile[r][c4+0] = v.x; tile[r][c4+1] = v.y; tile[r][c4+2] = v.z; tile[r][c4+3] = v.w;
        __syncthreads();
        uint2 o;
        o.x = (unsigned)f2b(tile[c4+0][r]*s) | ((unsigned)f2b(tile[c4+1][r]*s) << 16);
        o.y = (unsigned)f2b(tile[c4+2][r]*s) | ((unsigned)f2b(tile[c4+3][r]*s) << 16);
        int f = n0 + r;
        size_t drow;
        unsigned short* dst;
        if (wi == 0)      { dst = WqkvT; drow = f; }
        else if (wi == 1) { dst = WqkvT; drow = 1024 + (f >> 6) * 128 + (f & 63); }
        else if (wi == 2) { dst = WqkvT; drow = 1024 + (f >> 6) * 128 + 64 + (f & 63); }
        else              { dst = WoT;   drow = f; }
        *(uint2*)(dst + drow * DM + k0 + c4) = o;
    } else if (bid < 2048 + 4096 + 12) {
        int n = (bid - 6144) * 256 + t;
        float v;
        if (n < 1024) v = bq[n];
        else {
            int kv = (n - 1024) >> 7, r = (n - 1024) & 127;
            v = (r < 64) ? 0.125f * bk[kv * 64 + r] : bv[kv * 64 + (r - 64)];
        }
        biasq[n] = v;
        if (bid == 6144 && t < 32) done[t] = 0u;
    } else {
        int i = ((bid - 6156) * 256 + t) * 4;
        float4 z; z.x = z.y = z.z = z.w = 0.f;
        *(float4*)(KtV + i) = z;
    }
}

// ---------------- fused QKV projection + K^T V + zmat finisher ---------------
// 1-D grid of 768, XCD-swizzled. nt<8 -> Q blocks. nt>=8 -> head h=nt-8:
// K/V stay in regs, LDS-transposed, 16 MFMAs -> partial K^T V atomicAdd.
// LAST of the 16 blocks per (b,h) computes ZT[b][:,h-slice] = WoT @ KtV[bh].
// KtV is read with AGENT-scope atomic loads: plain loads can hit stale
// per-XCD L2 lines within one dispatch (round-12 replay divergence).
__global__ __launch_bounds__(256)
void qkv_fused_kernel(const unsigned short* __restrict__ A,
                      const unsigned short* __restrict__ Bt,
                      const float* __restrict__ biasq,
                      const unsigned short* __restrict__ WoT,
                      unsigned short* __restrict__ Qb,
                      float* __restrict__ KtV,
                      unsigned short* __restrict__ ZT,
                      unsigned* __restrict__ done)
{
    __shared__ __align__(16) char smem[34816];
    __shared__ unsigned lastflag;
    unsigned short* As = (unsigned short*)smem;
    unsigned short* Bs = (unsigned short*)(smem + 8192);

    const int bid = blockIdx.x;
    const int xcd = bid & 7, local = bid >> 3;    // 96 blocks per XCD
    const int mt = xcd * 4 + (local & 3);         // 0..31
    const int nt = local >> 2;                    // 0..23
    const int m0 = mt * 128, n0 = nt * 128;

    const int t = threadIdx.x;
    const int w = t >> 6, lane = t & 63;
    const int quad = lane >> 4, l16 = lane & 15;
    const int wm = w >> 1, wn = w & 1;

    f32x4 acc[4][4];
    #pragma unroll
    for (int i = 0; i < 4; i++)
        #pragma unroll
        for (int j = 0; j < 4; j++)
            #pragma unroll
            for (int r = 0; r < 4; r++) acc[i][j][r] = 0.f;

    const int srow = t >> 2;
    const int schunk = t & 3;

    for (int kk = 0; kk < DM; kk += 32) {
        #pragma unroll
        for (int p = 0; p < 2; p++) {
            int row = p * 64 + srow;
            int g = schunk ^ ((row >> 1) & 3);
            gld_lds16(A  + (size_t)(m0 + row) * DM + kk + g * 8,
                      (char*)As + p * 4096 + w * 1024);
            gld_lds16(Bt + (size_t)(n0 + row) * DM + kk + g * 8,
                      (char*)Bs + p * 4096 + w * 1024);
        }
        __syncthreads();

        short8 afr[4], bfr[4];
        #pragma unroll
        for (int i = 0; i < 4; i++) {
            int am = wm * 64 + i * 16 + l16;
            afr[i] = *(const short8*)((const char*)As + am * 64 + ((quad ^ ((am >> 1) & 3)) << 4));
            int bn = wn * 64 + i * 16 + l16;
            bfr[i] = *(const short8*)((const char*)Bs + bn * 64 + ((quad ^ ((bn >> 1) & 3)) << 4));
        }
        #pragma unroll
        for (int i = 0; i < 4; i++)
            #pragma unroll
            for (int j = 0; j < 4; j++)
                acc[i][j] = __builtin_amdgcn_mfma_f32_16x16x32_bf16(afr[i], bfr[j], acc[i][j], 0, 0, 0);
        __syncthreads();
    }

    #pragma unroll
    for (int j = 0; j < 4; j++) {
        float bv = biasq[n0 + wn * 64 + j * 16 + l16];
        #pragma unroll
        for (int i = 0; i < 4; i++)
            #pragma unroll
            for (int r = 0; r < 4; r++) acc[i][j][r] += bv;
    }

    if (nt < 8) {
        #pragma unroll
        for (int j = 0; j < 4; j++) {
            int col = n0 + wn * 64 + j * 16 + l16;
            #pragma unroll
            for (int i = 0; i < 4; i++) {
                #pragma unroll
                for (int r = 0; r < 4; r++) {
                    int row = m0 + wm * 64 + i * 16 + quad * 4 + r;
                    Qb[(size_t)row * DM + col] = f2b(acc[i][j][r]);
                }
            }
        }
        return;
    }

    // ---- KV block: head h; tile cols 0..63 = K_h, 64..127 = V_h ----
    const int h  = nt - 8;
    const int b  = m0 >> 11;
    const int bh = b * NH + h;
    unsigned short (*Xt)[136] = (unsigned short (*)[136])smem;   // [c][l]

    #pragma unroll
    for (int j = 0; j < 4; j++) {
        int c = wn * 64 + j * 16 + l16;
        #pragma unroll
        for (int i = 0; i < 4; i++) {
            int l0 = wm * 64 + i * 16 + quad * 4;
            uint2 o;
            o.x = (unsigned)f2b(acc[i][j][0]) | ((unsigned)f2b(acc[i][j][1]) << 16);
            o.y = (unsigned)f2b(acc[i][j][2]) | ((unsigned)f2b(acc[i][j][3]) << 16);
            *(uint2*)&Xt[c][l0] = o;
        }
    }
    __syncthreads();

    f32x4 kacc[4];
    #pragma unroll
    for (int j = 0; j < 4; j++)
        #pragma unroll
        for (int r = 0; r < 4; r++) kacc[j][r] = 0.f;

    #pragma unroll
    for (int ks = 0; ks < 4; ks++) {
        short8 af = *(const short8*)&Xt[w * 16 + l16][ks * 32 + quad * 8];
        #pragma unroll
        for (int j = 0; j < 4; j++) {
            short8 bfr = *(const short8*)&Xt[64 + j * 16 + l16][ks * 32 + quad * 8];
            kacc[j] = __builtin_amdgcn_mfma_f32_16x16x32_bf16(af, bfr, kacc[j], 0, 0, 0);
        }
    }

    float* dst = KtV + (size_t)bh * 64 * 64;
    #pragma unroll
    for (int j = 0; j < 4; j++) {
        int col = j * 16 + l16;
        #pragma unroll
        for (int r = 0; r < 4; r++) {
            int row = w * 16 + quad * 4 + r;
            atomicAdd(dst + row * 64 + col, kacc[j][r]);
        }
    }

    // ---- zmat finisher: last of the 16 blocks for this (b,h) ----
    __syncthreads();   // drains all lanes' atomics (vmcnt(0) before barrier)
    if (t == 0) {
        unsigned old = __hip_atomic_fetch_add(done + bh, 1u,
                                              __ATOMIC_ACQ_REL, __HIP_MEMORY_SCOPE_AGENT);
        lastflag = (old == 15u) ? 1u : 0u;
    }
    __syncthreads();
    if (!lastflag) return;

    unsigned short (*Asl)[72] = (unsigned short (*)[72])smem;           // [n][d2]
    unsigned short (*Bsl)[72] = (unsigned short (*)[72])(smem + 9216);  // [d1][d2]
    const int row = t >> 2, c0 = (t & 3) << 4;

    {   // stage KtV[bh] -> bf16 [d1][d2]; AGENT-scope loads bypass stale L1/L2
        const float* kp = KtV + ((size_t)bh * 64 + row) * 64 + c0;
        #pragma unroll
        for (int jj = 0; jj < 16; jj++) {
            float v = __hip_atomic_load(kp + jj, __ATOMIC_ACQUIRE,
                                        __HIP_MEMORY_SCOPE_AGENT);
            Bsl[row][c0 + jj] = f2b(v);
        }
    }
    __syncthreads();

    short8 kfr[2][4];  // hoisted KtV fragments
    #pragma unroll
    for (int ks = 0; ks < 2; ks++)
        #pragma unroll
        for (int j = 0; j < 4; j++)
            kfr[ks][j] = *(const short8*)&Bsl[j * 16 + l16][ks * 32 + quad * 8];

    unsigned short* zb = ZT + (size_t)b * 1024 * 1024 + (size_t)h * DH;
    for (int nt0 = 0; nt0 < 16; nt0++) {
        const int n0z = nt0 * 64;
        const unsigned short* ap = WoT + (size_t)(n0z + row) * DM + h * DH + c0;
        uint4 a0 = *(const uint4*)ap;
        uint4 a1 = *(const uint4*)(ap + 8);
        __syncthreads();                 // Asl write-after-read guard
        *(uint4*)&Asl[row][c0]     = a0;
        *(uint4*)&Asl[row][c0 + 8] = a1;
        __syncthreads();

        f32x4 zacc[4];
        #pragma unroll
        for (int j = 0; j < 4; j++)
            #pragma unroll
            for (int r = 0; r < 4; r++) zacc[j][r] = 0.f;

        #pragma unroll
        for (int ks = 0; ks < 2; ks++) {
            short8 af = *(const short8*)&Asl[w * 16 + l16][ks * 32 + quad * 8];
            #pragma unroll
            for (int j = 0; j < 4; j++)
                zacc[j] = __builtin_amdgcn_mfma_f32_16x16x32_bf16(af, kfr[ks][j], zacc[j], 0, 0, 0);
        }

        #pragma unroll
        for (int j = 0; j < 4; j++) {
            int col = j * 16 + l16;       // d1
            #pragma unroll
            for (int r = 0; r < 4; r++) {
                int zr = n0z + w * 16 + quad * 4 + r;   // n
                zb[(size_t)zr * 1024 + col] = f2b(zacc[j][r]);
            }
        }
    }
}

// ---------------- out = Q @ ZT[b] + bo: 128x64 tile, BK=64, XCD-swizzled -----
__global__ __launch_bounds__(256)
void out_gemm_kernel(const unsigned short* __restrict__ A,
                     const unsigned short* __restrict__ Bt,
                     const float* __restrict__ bias,
                     float* __restrict__ C)
{
    __shared__ __align__(16) unsigned short As[128 * 64];   // 16 KB
    __shared__ __align__(16) unsigned short Bs[64 * 64];    // 8 KB

    const int bid = blockIdx.x;
    const int xcd = bid & 7, local = bid >> 3;   // 64 per XCD
    const int mt = xcd * 4 + (local & 3);        // 0..31
    const int nt = local >> 2;                   // 0..15
    const int m0 = mt * 128, n0 = nt * 64;

    const int t = threadIdx.x;
    const int w = t >> 6, lane = t & 63;
    const int quad = lane >> 4, l16 = lane & 15;

    const unsigned short* Btb = Bt + (size_t)(m0 >> 11) * 1024 * 1024;

    f32x4 acc[2][4];
    #pragma unroll
    for (int i = 0; i < 2; i++)
        #pragma unroll
        for (int j = 0; j < 4; j++)
            #pragma unroll
            for (int r = 0; r < 4; r++) acc[i][j][r] = 0.f;

    for (int kk = 0; kk < DM; kk += 64) {
        #pragma unroll
        for (int p = 0; p < 4; p++) {              // A: 128 rows x 8 chunks
            int c = p * 256 + t;
            int row = c >> 3, slot = c & 7;
            int g = slot ^ ((row >> 1) & 7);
            gld_lds16(A + (size_t)(m0 + row) * DM + kk + g * 8,
                      (char*)As + p * 4096 + w * 1024);
        }
        #pragma unroll
        for (int p = 0; p < 2; p++) {              // B: 64 rows x 8 chunks
            int c = p * 256 + t;
            int row = c >> 3, slot = c & 7;
            int g = slot ^ ((row >> 1) & 7);
            gld_lds16(Btb + (size_t)(n0 + row) * DM + kk + g * 8,
                      (char*)Bs + p * 4096 + w * 1024);
        }
        __syncthreads();

        #pragma unroll
        for (int ks = 0; ks < 2; ks++) {
            int kc = ks * 4 + quad;
            short8 afr[2], bfr[4];
            #pragma unroll
            for (int i = 0; i < 2; i++) {
                int am = w * 32 + i * 16 + l16;
                afr[i] = *(const short8*)((const char*)As + am * 128 + ((kc ^ ((am >> 1) & 7)) << 4));
            }
            #pragma unroll
            for (int j = 0; j < 4; j++) {
                int bn = j * 16 + l16;
                bfr[j] = *(const short8*)((const char*)Bs + bn * 128 + ((kc ^ ((bn >> 1) & 7)) << 4));
            }
            #pragma unroll
            for (int i = 0; i < 2; i++)
                #pragma unroll
                for (int j = 0; j < 4; j++)
                    acc[i][j] = __builtin_amdgcn_mfma_f32_16x16x32_bf16(afr[i], bfr[j], acc[i][j], 0, 0, 0);
        }
        __syncthreads();
    }

    #pragma unroll
    for (int j = 0; j < 4; j++) {
        int col = n0 + j * 16 + l16;
        float bv = bias[col];
        #pragma unroll
        for (int i = 0; i < 2; i++) {
            #pragma unroll
            for (int r = 0; r < 4; r++) {
                int row = m0 + w * 32 + i * 16 + quad * 4 + r;
                C[(size_t)row * DM + col] = acc[i][j][r] + bv;
            }
        }
    }
}

// ---------------- launch ------------------------------------------------------

extern "C" void kernel_launch(void* const* d_in, const int* in_sizes, int n_in,
                              void* d_out, int out_size, void* d_ws, size_t ws_size,
                              hipStream_t stream)
{
    const float* x  = (const float*)d_in[0];
    const float* Wq = (const float*)d_in[1];
    const float* bq = (const float*)d_in[2];
    const float* Wk = (const float*)d_in[3];
    const float* bk = (const float*)d_in[4];
    const float* Wv = (const float*)d_in[5];
    const float* bv = (const float*)d_in[6];
    const float* Wo = (const float*)d_in[7];
    const float* bo = (const float*)d_in[8];

    char* ws = (char*)d_ws;
    unsigned short* xb    = (unsigned short*)(ws);                              // 8 MB
    unsigned short* WqkvT = (unsigned short*)(ws + (size_t)8  * 1024 * 1024);   // 6 MB
    unsigned short* WoT   = (unsigned short*)(ws + (size_t)14 * 1024 * 1024);   // 2 MB
    float*          biasq = (float*)         (ws + (size_t)16 * 1024 * 1024);   // 12 KB
    unsigned short* Qb    = (unsigned short*)(ws + (size_t)17 * 1024 * 1024);   // 8 MB
    unsigned short* ZT    = (unsigned short*)(ws + (size_t)25 * 1024 * 1024);   // 4 MB
    float*          KtV   = (float*)         (ws + (size_t)29 * 1024 * 1024);   // 512 KB
    unsigned*       done  = (unsigned*)      (ws + (size_t)29 * 1024 * 1024 + 512 * 1024);

    setup_kernel<<<6284, 256, 0, stream>>>(x, Wq, Wk, Wv, Wo, bq, bk, bv,
                                           xb, WqkvT, WoT, biasq, KtV, done);

    qkv_fused_kernel<<<768, 256, 0, stream>>>(xb, WqkvT, biasq, WoT, Qb, KtV, ZT, done);

    out_gemm_kernel<<<512, 256, 0, stream>>>(Qb, ZT, bo, (float*)d_out);
}

// Round 14
// 143.758 us; speedup vs baseline: 1.5259x; 1.5259x over previous
//
#include <hip/hip_runtime.h>
#include <stdint.h>

#define B_ 2
#define L_ 2048
#define DM 1024
#define NH 16
#define DH 64
#define M_ (B_*L_)     // 4096
#define NQKV 3072

typedef short short8 __attribute__((ext_vector_type(8)));
typedef float f32x4 __attribute__((ext_vector_type(4)));

__device__ __forceinline__ unsigned short f2b(float f) {
    union { float f; unsigned int u; } v; v.f = f;
    unsigned int u = v.u;
    return (unsigned short)((u + 0x7fffu + ((u >> 16) & 1u)) >> 16);   // RNE
}

__device__ __forceinline__ void gld_lds16(const void* g, void* l) {
    __builtin_amdgcn_global_load_lds(
        (const __attribute__((address_space(1))) void*)g,
        (__attribute__((address_space(3))) void*)l, 16, 0, 0);
}

// ---------------- fused setup (round-7 proven) -------------------------------
__global__ __launch_bounds__(256)
void setup_kernel(const float* __restrict__ x,
                  const float* __restrict__ Wq, const float* __restrict__ Wk,
                  const float* __restrict__ Wv, const float* __restrict__ Wo,
                  const float* __restrict__ bq, const float* __restrict__ bk,
                  const float* __restrict__ bv,
                  unsigned short* __restrict__ xb, unsigned short* __restrict__ WqkvT,
                  unsigned short* __restrict__ WoT, float* __restrict__ biasq,
                  float* __restrict__ KtV)
{
    __shared__ float tile[32][33];
    const int bid = blockIdx.x;
    const int t = threadIdx.x;

    if (bid < 2048) {
        int i = (bid * 256 + t) * 8;
        float4 a0 = *(const float4*)(x + i);
        float4 a1 = *(const float4*)(x + i + 4);
        uint4 p;
        p.x = (unsigned)f2b(a0.x) | ((unsigned)f2b(a0.y) << 16);
        p.y = (unsigned)f2b(a0.z) | ((unsigned)f2b(a0.w) << 16);
        p.z = (unsigned)f2b(a1.x) | ((unsigned)f2b(a1.y) << 16);
        p.w = (unsigned)f2b(a1.z) | ((unsigned)f2b(a1.w) << 16);
        *(uint4*)(xb + i) = p;
    } else if (bid < 2048 + 4096) {
        int wb = bid - 2048;
        int wi = wb >> 10;                // 0=Wq 1=Wk 2=Wv 3=Wo
        int tid = wb & 1023;
        const float* W = (wi == 0) ? Wq : (wi == 1) ? Wk : (wi == 2) ? Wv : Wo;
        float s = (wi == 1) ? 0.125f : 1.0f;
        int n0 = (tid & 31) * 32, k0 = (tid >> 5) * 32;
        int r = t >> 3, c4 = (t & 7) << 2;
        float4 v = *(const float4*)(W + (size_t)(k0 + r) * DM + n0 + c4);
        tile[r][c4+0] = v.x; tile[r][c4+1] = v.y; tile[r][c4+2] = v.z; tile[r][c4+3] = v.w;
        __syncthreads();
        uint2 o;
        o.x = (unsigned)f2b(tile[c4+0][r]*s) | ((unsigned)f2b(tile[c4+1][r]*s) << 16);
        o.y = (unsigned)f2b(tile[c4+2][r]*s) | ((unsigned)f2b(tile[c4+3][r]*s) << 16);
        int f = n0 + r;
        size_t drow;
        unsigned short* dst;
        if (wi == 0)      { dst = WqkvT; drow = f; }
        else if (wi == 1) { dst = WqkvT; drow = 1024 + (f >> 6) * 128 + (f & 63); }
        else if (wi == 2) { dst = WqkvT; drow = 1024 + (f >> 6) * 128 + 64 + (f & 63); }
        else              { dst = WoT;   drow = f; }
        *(uint2*)(dst + drow * DM + k0 + c4) = o;
    } else if (bid < 2048 + 4096 + 12) {
        int n = (bid - 6144) * 256 + t;
        float v;
        if (n < 1024) v = bq[n];
        else {
            int kv = (n - 1024) >> 7, r = (n - 1024) & 127;
            v = (r < 64) ? 0.125f * bk[kv * 64 + r] : bv[kv * 64 + (r - 64)];
        }
        biasq[n] = v;
    } else {
        int i = ((bid - 6156) * 256 + t) * 4;
        float4 z; z.x = z.y = z.z = z.w = 0.f;
        *(float4*)(KtV + i) = z;
    }
}

// ---------------- fused QKV projection + K^T V epilogue (round-7 proven) -----
__global__ __launch_bounds__(256)
void qkv_fused_kernel(const unsigned short* __restrict__ A,
                      const unsigned short* __restrict__ Bt,
                      const float* __restrict__ biasq,
                      unsigned short* __restrict__ Qb,
                      float* __restrict__ KtV)
{
    __shared__ __align__(16) char smem[34816];
    unsigned short* As = (unsigned short*)smem;
    unsigned short* Bs = (unsigned short*)(smem + 8192);

    const int bid = blockIdx.x;
    const int xcd = bid & 7, local = bid >> 3;    // 96 blocks per XCD
    const int mt = xcd * 4 + (local & 3);         // 0..31
    const int nt = local >> 2;                    // 0..23
    const int m0 = mt * 128, n0 = nt * 128;

    const int t = threadIdx.x;
    const int w = t >> 6, lane = t & 63;
    const int quad = lane >> 4, l16 = lane & 15;
    const int wm = w >> 1, wn = w & 1;

    f32x4 acc[4][4];
    #pragma unroll
    for (int i = 0; i < 4; i++)
        #pragma unroll
        for (int j = 0; j < 4; j++)
            #pragma unroll
            for (int r = 0; r < 4; r++) acc[i][j][r] = 0.f;

    const int srow = t >> 2;
    const int schunk = t & 3;

    for (int kk = 0; kk < DM; kk += 32) {
        #pragma unroll
        for (int p = 0; p < 2; p++) {
            int row = p * 64 + srow;
            int g = schunk ^ ((row >> 1) & 3);
            gld_lds16(A  + (size_t)(m0 + row) * DM + kk + g * 8,
                      (char*)As + p * 4096 + w * 1024);
            gld_lds16(Bt + (size_t)(n0 + row) * DM + kk + g * 8,
                      (char*)Bs + p * 4096 + w * 1024);
        }
        __syncthreads();

        short8 afr[4], bfr[4];
        #pragma unroll
        for (int i = 0; i < 4; i++) {
            int am = wm * 64 + i * 16 + l16;
            afr[i] = *(const short8*)((const char*)As + am * 64 + ((quad ^ ((am >> 1) & 3)) << 4));
            int bn = wn * 64 + i * 16 + l16;
            bfr[i] = *(const short8*)((const char*)Bs + bn * 64 + ((quad ^ ((bn >> 1) & 3)) << 4));
        }
        #pragma unroll
        for (int i = 0; i < 4; i++)
            #pragma unroll
            for (int j = 0; j < 4; j++)
                acc[i][j] = __builtin_amdgcn_mfma_f32_16x16x32_bf16(afr[i], bfr[j], acc[i][j], 0, 0, 0);
        __syncthreads();
    }

    #pragma unroll
    for (int j = 0; j < 4; j++) {
        float bv = biasq[n0 + wn * 64 + j * 16 + l16];
        #pragma unroll
        for (int i = 0; i < 4; i++)
            #pragma unroll
            for (int r = 0; r < 4; r++) acc[i][j][r] += bv;
    }

    if (nt < 8) {
        #pragma unroll
        for (int j = 0; j < 4; j++) {
            int col = n0 + wn * 64 + j * 16 + l16;
            #pragma unroll
            for (int i = 0; i < 4; i++) {
                #pragma unroll
                for (int r = 0; r < 4; r++) {
                    int row = m0 + wm * 64 + i * 16 + quad * 4 + r;
                    Qb[(size_t)row * DM + col] = f2b(acc[i][j][r]);
                }
            }
        }
        return;
    }

    // ---- KV block: head h; tile cols 0..63 = K_h, 64..127 = V_h ----
    const int h  = nt - 8;
    const int bh = (m0 >> 11) * NH + h;
    unsigned short (*Xt)[136] = (unsigned short (*)[136])smem;   // [c][l]

    #pragma unroll
    for (int j = 0; j < 4; j++) {
        int c = wn * 64 + j * 16 + l16;
        #pragma unroll
        for (int i = 0; i < 4; i++) {
            int l0 = wm * 64 + i * 16 + quad * 4;
            uint2 o;
            o.x = (unsigned)f2b(acc[i][j][0]) | ((unsigned)f2b(acc[i][j][1]) << 16);
            o.y = (unsigned)f2b(acc[i][j][2]) | ((unsigned)f2b(acc[i][j][3]) << 16);
            *(uint2*)&Xt[c][l0] = o;
        }
    }
    __syncthreads();

    f32x4 kacc[4];
    #pragma unroll
    for (int j = 0; j < 4; j++)
        #pragma unroll
        for (int r = 0; r < 4; r++) kacc[j][r] = 0.f;

    #pragma unroll
    for (int ks = 0; ks < 4; ks++) {
        short8 af = *(const short8*)&Xt[w * 16 + l16][ks * 32 + quad * 8];
        #pragma unroll
        for (int j = 0; j < 4; j++) {
            short8 bfr = *(const short8*)&Xt[64 + j * 16 + l16][ks * 32 + quad * 8];
            kacc[j] = __builtin_amdgcn_mfma_f32_16x16x32_bf16(af, bfr, kacc[j], 0, 0, 0);
        }
    }

    float* dst = KtV + (size_t)bh * 64 * 64;
    #pragma unroll
    for (int j = 0; j < 4; j++) {
        int col = j * 16 + l16;
        #pragma unroll
        for (int r = 0; r < 4; r++) {
            int row = w * 16 + quad * 4 + r;
            atomicAdd(dst + row * 64 + col, kacc[j][r]);
        }
    }
}

// ---------------- ZT[b][n][h*64+d1] = sum_d2 KtV[bh][d1][d2]*WoT[n][h*64+d2] --
__global__ __launch_bounds__(256)
void zmat_kernel(const unsigned short* __restrict__ WoT, const float* __restrict__ KtV,
                 unsigned short* __restrict__ ZT)
{
    __shared__ __align__(16) unsigned short Asl[64][72];  // [n][d2]
    __shared__ __align__(16) unsigned short Bsl[64][72];  // [d1][d2]

    const int bh = blockIdx.x, nt0 = blockIdx.y;
    const int b = bh >> 4, h = bh & 15;
    const int t = threadIdx.x;
    const int wave = t >> 6, lane = t & 63;
    const int quad = lane >> 4, l16 = lane & 15;
    const int n0 = nt0 * 64;
    const int row = t >> 2, c0 = (t & 3) << 4;

    const unsigned short* ap = WoT + (size_t)(n0 + row) * DM + h * DH + c0;
    *(uint4*)&Asl[row][c0]     = *(const uint4*)ap;
    *(uint4*)&Asl[row][c0 + 8] = *(const uint4*)(ap + 8);

    const float* kp = KtV + ((size_t)bh * 64 + row) * 64 + c0;
    #pragma unroll
    for (int j = 0; j < 16; j++) Bsl[row][c0 + j] = f2b(kp[j]);
    __syncthreads();

    f32x4 acc[4];
    #pragma unroll
    for (int i = 0; i < 4; i++)
        #pragma unroll
        for (int r = 0; r < 4; r++) acc[i][r] = 0.f;

    #pragma unroll
    for (int ks = 0; ks < 2; ks++) {
        short8 af = *(const short8*)&Asl[wave * 16 + l16][ks * 32 + quad * 8];
        #pragma unroll
        for (int nt = 0; nt < 4; nt++) {
            short8 bfr = *(const short8*)&Bsl[nt * 16 + l16][ks * 32 + quad * 8];
            acc[nt] = __builtin_amdgcn_mfma_f32_16x16x32_bf16(af, bfr, acc[nt], 0, 0, 0);
        }
    }

    unsigned short* zb = ZT + (size_t)b * 1024 * 1024 + (size_t)h * DH;
    #pragma unroll
    for (int nt = 0; nt < 4; nt++) {
        int col = nt * 16 + l16;
        #pragma unroll
        for (int r = 0; r < 4; r++) {
            int zr = n0 + wave * 16 + quad * 4 + r;
            zb[(size_t)zr * 1024 + col] = f2b(acc[nt][r]);
        }
    }
}

// ---------------- out = Q @ ZT[b] + bo: 128x64 tile, BK=64, XCD-swizzled -----
__global__ __launch_bounds__(256)
void out_gemm_kernel(const unsigned short* __restrict__ A,
                     const unsigned short* __restrict__ Bt,
                     const float* __restrict__ bias,
                     float* __restrict__ C)
{
    __shared__ __align__(16) unsigned short As[128 * 64];   // 16 KB
    __shared__ __align__(16) unsigned short Bs[64 * 64];    // 8 KB

    const int bid = blockIdx.x;
    const int xcd = bid & 7, local = bid >> 3;   // 64 per XCD
    const int mt = xcd * 4 + (local & 3);        // 0..31
    const int nt = local >> 2;                   // 0..15
    const int m0 = mt * 128, n0 = nt * 64;

    const int t = threadIdx.x;
    const int w = t >> 6, lane = t & 63;
    const int quad = lane >> 4, l16 = lane & 15;

    const unsigned short* Btb = Bt + (size_t)(m0 >> 11) * 1024 * 1024;

    f32x4 acc[2][4];
    #pragma unroll
    for (int i = 0; i < 2; i++)
        #pragma unroll
        for (int j = 0; j < 4; j++)
            #pragma unroll
            for (int r = 0; r < 4; r++) acc[i][j][r] = 0.f;

    for (int kk = 0; kk < DM; kk += 64) {
        #pragma unroll
        for (int p = 0; p < 4; p++) {              // A: 128 rows x 8 chunks
            int c = p * 256 + t;
            int row = c >> 3, slot = c & 7;
            int g = slot ^ ((row >> 1) & 7);
            gld_lds16(A + (size_t)(m0 + row) * DM + kk + g * 8,
                      (char*)As + p * 4096 + w * 1024);
        }
        #pragma unroll
        for (int p = 0; p < 2; p++) {              // B: 64 rows x 8 chunks
            int c = p * 256 + t;
            int row = c >> 3, slot = c & 7;
            int g = slot ^ ((row >> 1) & 7);
            gld_lds16(Btb + (size_t)(n0 + row) * DM + kk + g * 8,
                      (char*)Bs + p * 4096 + w * 1024);
        }
        __syncthreads();

        #pragma unroll
        for (int ks = 0; ks < 2; ks++) {
            int kc = ks * 4 + quad;
            short8 afr[2], bfr[4];
            #pragma unroll
            for (int i = 0; i < 2; i++) {
                int am = w * 32 + i * 16 + l16;
                afr[i] = *(const short8*)((const char*)As + am * 128 + ((kc ^ ((am >> 1) & 7)) << 4));
            }
            #pragma unroll
            for (int j = 0; j < 4; j++) {
                int bn = j * 16 + l16;
                bfr[j] = *(const short8*)((const char*)Bs + bn * 128 + ((kc ^ ((bn >> 1) & 7)) << 4));
            }
            #pragma unroll
            for (int i = 0; i < 2; i++)
                #pragma unroll
                for (int j = 0; j < 4; j++)
                    acc[i][j] = __builtin_amdgcn_mfma_f32_16x16x32_bf16(afr[i], bfr[j], acc[i][j], 0, 0, 0);
        }
        __syncthreads();
    }

    #pragma unroll
    for (int j = 0; j < 4; j++) {
        int col = n0 + j * 16 + l16;
        float bv = bias[col];
        #pragma unroll
        for (int i = 0; i < 2; i++) {
            #pragma unroll
            for (int r = 0; r < 4; r++) {
                int row = m0 + w * 32 + i * 16 + quad * 4 + r;
                C[(size_t)row * DM + col] = acc[i][j][r] + bv;
            }
        }
    }
}

// ---------------- launch ------------------------------------------------------

extern "C" void kernel_launch(void* const* d_in, const int* in_sizes, int n_in,
                              void* d_out, int out_size, void* d_ws, size_t ws_size,
                              hipStream_t stream)
{
    const float* x  = (const float*)d_in[0];
    const float* Wq = (const float*)d_in[1];
    const float* bq = (const float*)d_in[2];
    const float* Wk = (const float*)d_in[3];
    const float* bk = (const float*)d_in[4];
    const float* Wv = (const float*)d_in[5];
    const float* bv = (const float*)d_in[6];
    const float* Wo = (const float*)d_in[7];
    const float* bo = (const float*)d_in[8];

    char* ws = (char*)d_ws;
    unsigned short* xb    = (unsigned short*)(ws);                              // 8 MB
    unsigned short* WqkvT = (unsigned short*)(ws + (size_t)8  * 1024 * 1024);   // 6 MB
    unsigned short* WoT   = (unsigned short*)(ws + (size_t)14 * 1024 * 1024);   // 2 MB
    float*          biasq = (float*)         (ws + (size_t)16 * 1024 * 1024);   // 12 KB
    unsigned short* Qb    = (unsigned short*)(ws + (size_t)17 * 1024 * 1024);   // 8 MB
    unsigned short* ZT    = (unsigned short*)(ws + (size_t)25 * 1024 * 1024);   // 4 MB
    float*          KtV   = (float*)         (ws + (size_t)29 * 1024 * 1024);   // 512 KB

    setup_kernel<<<6284, 256, 0, stream>>>(x, Wq, Wk, Wv, Wo, bq, bk, bv,
                                           xb, WqkvT, WoT, biasq, KtV);

    qkv_fused_kernel<<<768, 256, 0, stream>>>(xb, WqkvT, biasq, Qb, KtV);

    zmat_kernel<<<dim3(B_ * NH, 16), 256, 0, stream>>>(WoT, KtV, ZT);

    out_gemm_kernel<<<512, 256, 0, stream>>>(Qb, ZT, bo, (float*)d_out);
}